// Round 12
// baseline (69.217 us; speedup 1.0000x reference)
//
#include <hip/hip_runtime.h>
#include <hip/hip_bf16.h>

#define B_   64
#define H_   1024
#define E_   512
#define V_   50000
#define S_   400
#define EXTV 50100        // V + 100
#define K2   2048         // 2H
#define KP   2560         // 2H + E
#define VP2  50048        // padded bf16-e row stride (mult of 16, >= 391*128)
#define NBLK2 391         // ceil(V / 128)
#define PSTR 400          // padded partial-sum stride (>= NBLK2)
#define KCH  16           // split-K chunks for mid GEMM

typedef float  f32x4  __attribute__((ext_vector_type(4)));
typedef __bf16 bf16x8 __attribute__((ext_vector_type(8)));
typedef unsigned short u16x4 __attribute__((ext_vector_type(4)));

typedef __attribute__((address_space(1))) const void gas_t;
typedef __attribute__((address_space(3))) void las_t;
#define GLL16(g, l) __builtin_amdgcn_global_load_lds((gas_t*)(g), (las_t*)(l), 16, 0, 0)

static __device__ __forceinline__ bf16x8 pack_bf16(f32x4 a, f32x4 b) {
    bf16x8 r;
    r[0] = (__bf16)a[0]; r[1] = (__bf16)a[1]; r[2] = (__bf16)a[2]; r[3] = (__bf16)a[3];
    r[4] = (__bf16)b[0]; r[5] = (__bf16)b[1]; r[6] = (__bf16)b[2]; r[7] = (__bf16)b[3];
    return r;
}

// ------- fused: mid GEMM (blocks 0..255) + p_gen (blocks 256..319) ----------
__global__ __launch_bounds__(256, 4) void k_midp(const float* __restrict__ dec,
                                                 const float* __restrict__ ctx,
                                                 const float* __restrict__ emb,
                                                 const float* __restrict__ Wm,
                                                 const float* __restrict__ Wp,
                                                 const float* __restrict__ bp,
                                                 float* __restrict__ pmid,
                                                 float* __restrict__ pg,
                                                 float* __restrict__ out1) {
    __shared__ float r[4];
    if (blockIdx.x < 256) {
        // ---- mid GEMM tile (split-K 16): M=64, N=1024, K=2048 ----
        int nt   = blockIdx.x & 15;        // h-tile of 64
        int kc   = blockIdx.x >> 4;        // K-chunk of 128
        int wave = threadIdx.x >> 6;
        int lane = threadIdx.x & 63;
        int lr   = lane & 15, lg = lane >> 4;
        int col  = nt * 64 + wave * 16 + lr;          // h index
        const float* xb   = (kc < 8) ? dec : ctx;
        int kbase         = (kc & 7) * 128;
        const float* wrow = Wm + (size_t)col * K2 + kc * 128 + lg * 8;
        const float* xrow = xb + (size_t)lr * H_ + kbase + lg * 8;

        f32x4 w0s[4], w1s[4];
#pragma unroll
        for (int p = 0; p < 4; ++p) {
            w0s[p] = *(const f32x4*)(wrow + p * 32);
            w1s[p] = *(const f32x4*)(wrow + p * 32 + 4);
        }
        f32x4 acc[4] = {};
#pragma unroll
        for (int i = 0; i < 4; ++i) {
            f32x4 a0[4], a1[4];
#pragma unroll
            for (int mf = 0; mf < 4; ++mf) {
                const float* xp = xrow + (size_t)(mf * 16) * H_ + i * 32;
                a0[mf] = *(const f32x4*)xp;
                a1[mf] = *(const f32x4*)(xp + 4);
            }
            bf16x8 bf = pack_bf16(w0s[i], w1s[i]);
#pragma unroll
            for (int mf = 0; mf < 4; ++mf) {
                bf16x8 af = pack_bf16(a0[mf], a1[mf]);
                acc[mf] = __builtin_amdgcn_mfma_f32_16x16x32_bf16(af, bf, acc[mf], 0, 0, 0);
            }
        }
#pragma unroll
        for (int mf = 0; mf < 4; ++mf)
#pragma unroll
            for (int q = 0; q < 4; ++q) {
                int row = mf * 16 + lg * 4 + q;       // batch index
                pmid[((size_t)kc * B_ + row) * H_ + col] = acc[mf][q];
            }
    } else {
        // ---- p_gen for batch b ----
        int b = blockIdx.x - 256;
        int tid = threadIdx.x;
        float s = 0.f;
        for (int k = tid; k < KP; k += 256) {
            float x;
            if (k < H_)          x = dec[b * H_ + k];
            else if (k < 2 * H_) x = ctx[b * H_ + k - H_];
            else                 x = emb[b * E_ + k - 2 * H_];
            s += x * Wp[k];
        }
#pragma unroll
        for (int m = 32; m >= 1; m >>= 1) s += __shfl_xor(s, m);
        int wave = tid >> 6, lane = tid & 63;
        if (lane == 0) r[wave] = s;
        __syncthreads();
        if (tid == 0) {
            float t = r[0] + r[1] + r[2] + r[3] + bp[0];
            float p = 1.f / (1.f + __expf(-t));
            pg[b]   = p;
            out1[b] = p;
        }
    }
}

// ---------------- reduce split-K partials, bias, tanh, -> bf16 --------------
__global__ __launch_bounds__(256) void k_mid_reduce(const float* __restrict__ pmid,
                                                    const float* __restrict__ bm,
                                                    __bf16* __restrict__ midb) {
    int idx = blockIdx.x * 256 + threadIdx.x;     // 65536
    int h = idx & (H_ - 1);
    int m = idx >> 10;
    float s = bm[h];
#pragma unroll
    for (int kc = 0; kc < KCH; ++kc) s += pmid[((size_t)kc * B_ + m) * H_ + h];
    midb[idx] = (__bf16)tanhf(s);
}

// ---------------- big GEMM: e = exp(clip(mid @ Wv^T + bv) - 50) -------------
// (unchanged — timed-proven structure: N=128/block, depth-3, vmcnt(5))
__global__ __launch_bounds__(256, 2) void k_gemm_vocab(const __bf16* __restrict__ midb,
                                                       const float* __restrict__ Wv,
                                                       const float* __restrict__ bv,
                                                       __bf16* __restrict__ e,
                                                       float* __restrict__ psum) {
    __shared__ __align__(16) char ldsW[3 * 16384];   // 48 KB: [buf][col 0..127][128B]
    __shared__ __align__(16) char ldsA[3 * 4096];    // 12 KB: [buf][row 0..63][64B]
    __shared__ float wsum[4][64];

    int tid  = threadIdx.x;
    int wave = tid >> 6;
    int lane = tid & 63;
    int lr   = lane & 15, lg = lane >> 4;
    int blk  = blockIdx.x;
    int colBase = blk * 128;

    const char* srcW[4];
#pragma unroll
    for (int j = 0; j < 4; ++j) {
        int c = colBase + wave * 32 + j * 8 + (lane >> 3);
        if (c >= V_) c = V_ - 1;
        int t = (lane & 7) ^ (c & 7);                  // swizzled source granule
        srcW[j] = (const char*)Wv + (size_t)c * 4096 + t * 16;
    }
    int arow = wave * 16 + (lane >> 2);
    int asw  = (((lane & 3) ^ ((lane >> 3) & 3)) << 4);
    const char* srcA = (const char*)midb + (size_t)arow * 2048 + asw;

    int colL0 = wave * 32 + lr;                        // cf=0 block-local col
    int colL1 = colL0 + 16;                            // cf=1
    int w00 = colL0 * 128 + ((((lg * 2)    ) ^ (colL0 & 7)) << 4);
    int w01 = colL0 * 128 + ((((lg * 2) + 1) ^ (colL0 & 7)) << 4);
    int w10 = colL1 * 128 + ((((lg * 2)    ) ^ (colL1 & 7)) << 4);
    int w11 = colL1 * 128 + ((((lg * 2) + 1) ^ (colL1 & 7)) << 4);
    int phiA  = (lr >> 1) & 3;
    int aoff0 = (0 * 16 + lr) * 64 + ((lg ^ phiA) << 4);
    int aoff1 = (1 * 16 + lr) * 64 + ((lg ^ phiA) << 4);
    int aoff2 = (2 * 16 + lr) * 64 + ((lg ^ phiA) << 4);
    int aoff3 = (3 * 16 + lr) * 64 + ((lg ^ phiA) << 4);

    f32x4 acc00 = {}, acc01 = {}, acc02 = {}, acc03 = {};   // cf=0, m=0..3
    f32x4 acc10 = {}, acc11 = {}, acc12 = {}, acc13 = {};   // cf=1

#define STAGE(s) do {                                                           \
        char* _bW = ldsW + ((s) % 3) * 16384 + wave * 4096;                     \
        char* _bA = ldsA + ((s) % 3) * 4096 + wave * 1024;                      \
        GLL16(srcW[0] + (s) * 128, _bW);                                        \
        GLL16(srcW[1] + (s) * 128, _bW + 1024);                                 \
        GLL16(srcW[2] + (s) * 128, _bW + 2048);                                 \
        GLL16(srcW[3] + (s) * 128, _bW + 3072);                                 \
        GLL16(srcA    + (s) * 64,  _bA);                                        \
    } while (0)

    STAGE(0);
    STAGE(1);

#define VBODY(i, N, DOW) do {                                                   \
        __builtin_amdgcn_sched_barrier(0);                                      \
        asm volatile("s_waitcnt vmcnt(" #N ")" ::: "memory");                   \
        __builtin_amdgcn_sched_barrier(0);                                      \
        __builtin_amdgcn_s_barrier();                                           \
        if (DOW) STAGE((i) + 2);                                                \
        const char* wS = ldsW + ((i) % 3) * 16384;                              \
        const char* aS = ldsA + ((i) % 3) * 4096;                               \
        f32x4 x00 = *(const f32x4*)(wS + w00);                                  \
        f32x4 x01 = *(const f32x4*)(wS + w01);                                  \
        f32x4 x10 = *(const f32x4*)(wS + w10);                                  \
        f32x4 x11 = *(const f32x4*)(wS + w11);                                  \
        bf16x8 bf0 = pack_bf16(x00, x01);                                       \
        bf16x8 bf1 = pack_bf16(x10, x11);                                       \
        bf16x8 af0 = *(const bf16x8*)(aS + aoff0);                              \
        bf16x8 af1 = *(const bf16x8*)(aS + aoff1);                              \
        bf16x8 af2 = *(const bf16x8*)(aS + aoff2);                              \
        bf16x8 af3 = *(const bf16x8*)(aS + aoff3);                              \
        acc00 = __builtin_amdgcn_mfma_f32_16x16x32_bf16(af0, bf0, acc00, 0, 0, 0); \
        acc01 = __builtin_amdgcn_mfma_f32_16x16x32_bf16(af1, bf0, acc01, 0, 0, 0); \
        acc02 = __builtin_amdgcn_mfma_f32_16x16x32_bf16(af2, bf0, acc02, 0, 0, 0); \
        acc03 = __builtin_amdgcn_mfma_f32_16x16x32_bf16(af3, bf0, acc03, 0, 0, 0); \
        acc10 = __builtin_amdgcn_mfma_f32_16x16x32_bf16(af0, bf1, acc10, 0, 0, 0); \
        acc11 = __builtin_amdgcn_mfma_f32_16x16x32_bf16(af1, bf1, acc11, 0, 0, 0); \
        acc12 = __builtin_amdgcn_mfma_f32_16x16x32_bf16(af2, bf1, acc12, 0, 0, 0); \
        acc13 = __builtin_amdgcn_mfma_f32_16x16x32_bf16(af3, bf1, acc13, 0, 0, 0); \
    } while (0)

    VBODY(0, 5, 1);  VBODY(1, 5, 1);  VBODY(2, 5, 1);  VBODY(3, 5, 1);
    VBODY(4, 5, 1);  VBODY(5, 5, 1);  VBODY(6, 5, 1);  VBODY(7, 5, 1);
    VBODY(8, 5, 1);  VBODY(9, 5, 1);  VBODY(10, 5, 1); VBODY(11, 5, 1);
    VBODY(12, 5, 1); VBODY(13, 5, 1); VBODY(14, 5, 1); VBODY(15, 5, 1);
    VBODY(16, 5, 1); VBODY(17, 5, 1); VBODY(18, 5, 1); VBODY(19, 5, 1);
    VBODY(20, 5, 1); VBODY(21, 5, 1); VBODY(22, 5, 1); VBODY(23, 5, 1);
    VBODY(24, 5, 1); VBODY(25, 5, 1); VBODY(26, 5, 1); VBODY(27, 5, 1);
    VBODY(28, 5, 1); VBODY(29, 5, 1); VBODY(30, 5, 0); VBODY(31, 0, 0);
#undef VBODY
#undef STAGE

    int gc0 = colBase + colL0;
    int gc1 = colBase + colL1;
    bool v0 = gc0 < V_, v1 = gc1 < V_;
    float b0 = v0 ? bv[gc0] : 0.f;
    float b1 = v1 ? bv[gc1] : 0.f;
    f32x4 accA[4] = {acc00, acc01, acc02, acc03};
    f32x4 accB[4] = {acc10, acc11, acc12, acc13};
#pragma unroll
    for (int mf = 0; mf < 4; ++mf) {
#pragma unroll
        for (int q = 0; q < 4; ++q) {
            int row = mf * 16 + lg * 4 + q;       // batch index
            float l0 = fminf(fmaxf(accA[mf][q] + b0, -50.f), 50.f);
            float l1 = fminf(fmaxf(accB[mf][q] + b1, -50.f), 50.f);
            float e0 = v0 ? __expf(l0 - 50.f) : 0.f;
            float e1 = v1 ? __expf(l1 - 50.f) : 0.f;
            if (v0) e[(size_t)row * VP2 + gc0] = (__bf16)e0;
            if (v1) e[(size_t)row * VP2 + gc1] = (__bf16)e1;
            float s = e0 + e1;
            s += __shfl_xor(s, 1); s += __shfl_xor(s, 2);
            s += __shfl_xor(s, 4); s += __shfl_xor(s, 8);
            if (lr == 0) wsum[wave][row] = s;
        }
    }
    __syncthreads();
    if (threadIdx.x < 64) {
        int row = threadIdx.x;
        float t = wsum[0][row] + wsum[1][row] + wsum[2][row] + wsum[3][row];
        psum[(size_t)row * PSTR + blk] = t;
    }
}

// ------- fused Z-reduce + normalize + outputs (vectorized x4) ---------------
__global__ __launch_bounds__(256) void k_finalz(const __bf16* __restrict__ e,
                                                const float* __restrict__ psum,
                                                const float* __restrict__ pg,
                                                float* __restrict__ out0,
                                                float* __restrict__ out2) {
    int b   = blockIdx.x >> 3;
    int sub = blockIdx.x & 7;
    int tid = threadIdx.x;

    float s = 0.f;
    for (int i = tid; i < NBLK2; i += 256) s += psum[(size_t)b * PSTR + i];
#pragma unroll
    for (int m = 32; m >= 1; m >>= 1) s += __shfl_xor(s, m);
    __shared__ float r[4];
    __shared__ float zsh;
    int wave = tid >> 6, lane = tid & 63;
    if (lane == 0) r[wave] = s;
    __syncthreads();
    if (tid == 0) zsh = 1.f / (r[0] + r[1] + r[2] + r[3]);
    __syncthreads();
    float zinv = zsh;
    float p = pg[b];

    int v4beg = sub * 1563;
    int v4end = v4beg + 1563;
    if (v4end > 12500) v4end = 12500;
    const u16x4* erow = (const u16x4*)(e + (size_t)b * VP2);
    f32x4* o0 = (f32x4*)(out0 + (size_t)b * EXTV);
    f32x4* o2 = (f32x4*)(out2 + (size_t)b * V_);
    for (int v4 = v4beg + tid; v4 < v4end; v4 += 256) {
        u16x4 u = erow[v4];
        f32x4 vd;
        vd[0] = __uint_as_float((unsigned)u[0] << 16) * zinv;
        vd[1] = __uint_as_float((unsigned)u[1] << 16) * zinv;
        vd[2] = __uint_as_float((unsigned)u[2] << 16) * zinv;
        vd[3] = __uint_as_float((unsigned)u[3] << 16) * zinv;
        o2[v4] = vd;
        f32x4 g;
        g[0] = p * vd[0]; g[1] = p * vd[1]; g[2] = p * vd[2]; g[3] = p * vd[3];
        o0[v4] = g;
    }
    if (sub == 7 && tid < 100) out0[(size_t)b * EXTV + V_ + tid] = 0.f;
}

// ---------------- copy-distribution scatter --------------------------------
__global__ __launch_bounds__(256) void k_scatter(const float* __restrict__ attn,
                                                 const int* __restrict__ sid,
                                                 const int* __restrict__ oov,
                                                 const float* __restrict__ pg,
                                                 float* __restrict__ out0) {
    int idx = blockIdx.x * 256 + threadIdx.x;
    if (idx >= B_ * S_) return;
    int b = idx / S_;
    int m = oov[idx];
    int tgt = (m >= 0) ? (V_ + m) : sid[idx];
    float w = (1.f - pg[b]) * attn[idx];
    atomicAdd(out0 + (size_t)b * EXTV + tgt, w);
}

extern "C" void kernel_launch(void* const* d_in, const int* in_sizes, int n_in,
                              void* d_out, int out_size, void* d_ws, size_t ws_size,
                              hipStream_t stream) {
    const float* dec  = (const float*)d_in[0];
    const float* ctx  = (const float*)d_in[1];
    const float* emb  = (const float*)d_in[2];
    const float* attn = (const float*)d_in[3];
    const int*   sid  = (const int*)d_in[4];
    const int*   oov  = (const int*)d_in[5];
    // d_in[6] = vocab_size (known statically = 50000)
    const float* Wm   = (const float*)d_in[7];
    const float* bm   = (const float*)d_in[8];
    const float* Wp   = (const float*)d_in[9];
    const float* bp   = (const float*)d_in[10];
    const float* Wv   = (const float*)d_in[11];
    const float* bv   = (const float*)d_in[12];

    float* out0 = (float*)d_out;                  // final_dist [64][50100]
    float* out1 = out0 + (size_t)B_ * EXTV;       // p_gen      [64]
    float* out2 = out1 + B_;                      // vocab_dist [64][50000]

    __bf16* e    = (__bf16*)d_ws;                            // [64][VP2] bf16
    float*  psum = (float*)((char*)d_ws + (size_t)B_ * VP2 * 2); // [64][PSTR]
    float*  pg   = psum + (size_t)B_ * PSTR;      // [64]
    float*  pmid = pg + 64;                       // [KCH][64][1024]
    __bf16* midb = (__bf16*)(pmid + (size_t)KCH * B_ * H_); // [64][1024]

    k_midp<<<320, 256, 0, stream>>>(dec, ctx, emb, Wm, Wp, bp, pmid, pg, out1);
    k_mid_reduce<<<(B_ * H_) / 256, 256, 0, stream>>>(pmid, bm, midb);
    k_gemm_vocab<<<NBLK2, 256, 0, stream>>>((const __bf16*)midb, Wv, bv, e, psum);
    k_finalz<<<B_ * 8, 256, 0, stream>>>((const __bf16*)e, psum, pg, out0, out2);
    k_scatter<<<(B_ * S_ + 255) / 256, 256, 0, stream>>>(attn, sid, oov, pg, out0);
}

// Round 13
// 64.934 us; speedup vs baseline: 1.0660x; 1.0660x over previous
//
#include <hip/hip_runtime.h>
#include <hip/hip_bf16.h>

#define B_   64
#define H_   1024
#define E_   512
#define V_   50000
#define S_   400
#define EXTV 50100        // V + 100
#define K2   2048         // 2H
#define KP   2560         // 2H + E
#define VP2  50048        // padded bf16-e row stride (mult of 16, >= 391*128)
#define NBLK2 391         // ceil(V / 128)
#define PSTR 400          // padded partial-sum stride (>= NBLK2)
#define KCH  16           // split-K chunks for mid GEMM

typedef float  f32x4  __attribute__((ext_vector_type(4)));
typedef __bf16 bf16x8 __attribute__((ext_vector_type(8)));
typedef unsigned short u16x4 __attribute__((ext_vector_type(4)));

typedef __attribute__((address_space(1))) const void gas_t;
typedef __attribute__((address_space(3))) void las_t;
#define GLL16(g, l) __builtin_amdgcn_global_load_lds((gas_t*)(g), (las_t*)(l), 16, 0, 0)

static __device__ __forceinline__ bf16x8 pack_bf16(f32x4 a, f32x4 b) {
    bf16x8 r;
    r[0] = (__bf16)a[0]; r[1] = (__bf16)a[1]; r[2] = (__bf16)a[2]; r[3] = (__bf16)a[3];
    r[4] = (__bf16)b[0]; r[5] = (__bf16)b[1]; r[6] = (__bf16)b[2]; r[7] = (__bf16)b[3];
    return r;
}

// ---------------- p_gen: 64 dots of length 2560 -----------------------------
__global__ __launch_bounds__(256) void k_pgen(const float* __restrict__ dec,
                                              const float* __restrict__ ctx,
                                              const float* __restrict__ emb,
                                              const float* __restrict__ Wp,
                                              const float* __restrict__ bp,
                                              float* __restrict__ pg,
                                              float* __restrict__ out1) {
    int b = blockIdx.x;
    int tid = threadIdx.x;
    float s = 0.f;
    for (int k = tid; k < KP; k += 256) {
        float x;
        if (k < H_)          x = dec[b * H_ + k];
        else if (k < 2 * H_) x = ctx[b * H_ + k - H_];
        else                 x = emb[b * E_ + k - 2 * H_];
        s += x * Wp[k];
    }
#pragma unroll
    for (int m = 32; m >= 1; m >>= 1) s += __shfl_xor(s, m);
    __shared__ float r[4];
    int wave = tid >> 6, lane = tid & 63;
    if (lane == 0) r[wave] = s;
    __syncthreads();
    if (tid == 0) {
        float t = r[0] + r[1] + r[2] + r[3] + bp[0];
        float p = 1.f / (1.f + __expf(-t));
        pg[b]   = p;
        out1[b] = p;
    }
}

// ---------------- mid GEMM (split-K 16): M=64, N=1024, K=2048 ---------------
__global__ __launch_bounds__(256, 4) void k_gemm_mid(const float* __restrict__ dec,
                                                     const float* __restrict__ ctx,
                                                     const float* __restrict__ Wm,
                                                     float* __restrict__ pmid) {
    int nt   = blockIdx.x;             // 0..15  (h-tile of 64)
    int kc   = blockIdx.y;             // 0..15  (K-chunk of 128)
    int wave = threadIdx.x >> 6;
    int lane = threadIdx.x & 63;
    int lr   = lane & 15, lg = lane >> 4;
    int col  = nt * 64 + wave * 16 + lr;          // h index
    const float* xb   = (kc < 8) ? dec : ctx;
    int kbase         = (kc & 7) * 128;
    const float* wrow = Wm + (size_t)col * K2 + kc * 128 + lg * 8;
    const float* xrow = xb + (size_t)lr * H_ + kbase + lg * 8;

    f32x4 w0s[4], w1s[4];
#pragma unroll
    for (int p = 0; p < 4; ++p) {
        w0s[p] = *(const f32x4*)(wrow + p * 32);
        w1s[p] = *(const f32x4*)(wrow + p * 32 + 4);
    }
    f32x4 acc[4] = {};
#pragma unroll
    for (int i = 0; i < 4; ++i) {
        f32x4 a0[4], a1[4];
#pragma unroll
        for (int mf = 0; mf < 4; ++mf) {
            const float* xp = xrow + (size_t)(mf * 16) * H_ + i * 32;
            a0[mf] = *(const f32x4*)xp;
            a1[mf] = *(const f32x4*)(xp + 4);
        }
        bf16x8 bf = pack_bf16(w0s[i], w1s[i]);
#pragma unroll
        for (int mf = 0; mf < 4; ++mf) {
            bf16x8 af = pack_bf16(a0[mf], a1[mf]);
            acc[mf] = __builtin_amdgcn_mfma_f32_16x16x32_bf16(af, bf, acc[mf], 0, 0, 0);
        }
    }
#pragma unroll
    for (int mf = 0; mf < 4; ++mf)
#pragma unroll
        for (int r = 0; r < 4; ++r) {
            int row = mf * 16 + lg * 4 + r;       // batch index
            pmid[((size_t)kc * B_ + row) * H_ + col] = acc[mf][r];
        }
}

// ---------------- reduce split-K partials, bias, tanh, -> bf16 --------------
__global__ __launch_bounds__(256) void k_mid_reduce(const float* __restrict__ pmid,
                                                    const float* __restrict__ bm,
                                                    __bf16* __restrict__ midb) {
    int idx = blockIdx.x * 256 + threadIdx.x;     // 65536
    int h = idx & (H_ - 1);
    int m = idx >> 10;
    float s = bm[h];
#pragma unroll
    for (int kc = 0; kc < KCH; ++kc) s += pmid[((size_t)kc * B_ + m) * H_ + h];
    midb[idx] = (__bf16)tanhf(s);
}

// ---------------- big GEMM: e = exp(clip(mid @ Wv^T + bv) - 50) -------------
// (timed-proven structure: N=128/block, depth-3, vmcnt(5), swizzled DMA)
__global__ __launch_bounds__(256, 2) void k_gemm_vocab(const __bf16* __restrict__ midb,
                                                       const float* __restrict__ Wv,
                                                       const float* __restrict__ bv,
                                                       __bf16* __restrict__ e,
                                                       float* __restrict__ psum) {
    __shared__ __align__(16) char ldsW[3 * 16384];   // 48 KB: [buf][col 0..127][128B]
    __shared__ __align__(16) char ldsA[3 * 4096];    // 12 KB: [buf][row 0..63][64B]
    __shared__ float wsum[4][64];

    int tid  = threadIdx.x;
    int wave = tid >> 6;
    int lane = tid & 63;
    int lr   = lane & 15, lg = lane >> 4;
    int blk  = blockIdx.x;
    int colBase = blk * 128;

    const char* srcW[4];
#pragma unroll
    for (int j = 0; j < 4; ++j) {
        int c = colBase + wave * 32 + j * 8 + (lane >> 3);
        if (c >= V_) c = V_ - 1;
        int t = (lane & 7) ^ (c & 7);                  // swizzled source granule
        srcW[j] = (const char*)Wv + (size_t)c * 4096 + t * 16;
    }
    int arow = wave * 16 + (lane >> 2);
    int asw  = (((lane & 3) ^ ((lane >> 3) & 3)) << 4);
    const char* srcA = (const char*)midb + (size_t)arow * 2048 + asw;

    int colL0 = wave * 32 + lr;                        // cf=0 block-local col
    int colL1 = colL0 + 16;                            // cf=1
    int w00 = colL0 * 128 + ((((lg * 2)    ) ^ (colL0 & 7)) << 4);
    int w01 = colL0 * 128 + ((((lg * 2) + 1) ^ (colL0 & 7)) << 4);
    int w10 = colL1 * 128 + ((((lg * 2)    ) ^ (colL1 & 7)) << 4);
    int w11 = colL1 * 128 + ((((lg * 2) + 1) ^ (colL1 & 7)) << 4);
    int phiA  = (lr >> 1) & 3;
    int aoff0 = (0 * 16 + lr) * 64 + ((lg ^ phiA) << 4);
    int aoff1 = (1 * 16 + lr) * 64 + ((lg ^ phiA) << 4);
    int aoff2 = (2 * 16 + lr) * 64 + ((lg ^ phiA) << 4);
    int aoff3 = (3 * 16 + lr) * 64 + ((lg ^ phiA) << 4);

    f32x4 acc00 = {}, acc01 = {}, acc02 = {}, acc03 = {};   // cf=0, m=0..3
    f32x4 acc10 = {}, acc11 = {}, acc12 = {}, acc13 = {};   // cf=1

#define STAGE(s) do {                                                           \
        char* _bW = ldsW + ((s) % 3) * 16384 + wave * 4096;                     \
        char* _bA = ldsA + ((s) % 3) * 4096 + wave * 1024;                      \
        GLL16(srcW[0] + (s) * 128, _bW);                                        \
        GLL16(srcW[1] + (s) * 128, _bW + 1024);                                 \
        GLL16(srcW[2] + (s) * 128, _bW + 2048);                                 \
        GLL16(srcW[3] + (s) * 128, _bW + 3072);                                 \
        GLL16(srcA    + (s) * 64,  _bA);                                        \
    } while (0)

    STAGE(0);
    STAGE(1);

#define VBODY(i, N, DOW) do {                                                   \
        __builtin_amdgcn_sched_barrier(0);                                      \
        asm volatile("s_waitcnt vmcnt(" #N ")" ::: "memory");                   \
        __builtin_amdgcn_sched_barrier(0);                                      \
        __builtin_amdgcn_s_barrier();                                           \
        if (DOW) STAGE((i) + 2);                                                \
        const char* wS = ldsW + ((i) % 3) * 16384;                              \
        const char* aS = ldsA + ((i) % 3) * 4096;                               \
        f32x4 x00 = *(const f32x4*)(wS + w00);                                  \
        f32x4 x01 = *(const f32x4*)(wS + w01);                                  \
        f32x4 x10 = *(const f32x4*)(wS + w10);                                  \
        f32x4 x11 = *(const f32x4*)(wS + w11);                                  \
        bf16x8 bf0 = pack_bf16(x00, x01);                                       \
        bf16x8 bf1 = pack_bf16(x10, x11);                                       \
        bf16x8 af0 = *(const bf16x8*)(aS + aoff0);                              \
        bf16x8 af1 = *(const bf16x8*)(aS + aoff1);                              \
        bf16x8 af2 = *(const bf16x8*)(aS + aoff2);                              \
        bf16x8 af3 = *(const bf16x8*)(aS + aoff3);                              \
        acc00 = __builtin_amdgcn_mfma_f32_16x16x32_bf16(af0, bf0, acc00, 0, 0, 0); \
        acc01 = __builtin_amdgcn_mfma_f32_16x16x32_bf16(af1, bf0, acc01, 0, 0, 0); \
        acc02 = __builtin_amdgcn_mfma_f32_16x16x32_bf16(af2, bf0, acc02, 0, 0, 0); \
        acc03 = __builtin_amdgcn_mfma_f32_16x16x32_bf16(af3, bf0, acc03, 0, 0, 0); \
        acc10 = __builtin_amdgcn_mfma_f32_16x16x32_bf16(af0, bf1, acc10, 0, 0, 0); \
        acc11 = __builtin_amdgcn_mfma_f32_16x16x32_bf16(af1, bf1, acc11, 0, 0, 0); \
        acc12 = __builtin_amdgcn_mfma_f32_16x16x32_bf16(af2, bf1, acc12, 0, 0, 0); \
        acc13 = __builtin_amdgcn_mfma_f32_16x16x32_bf16(af3, bf1, acc13, 0, 0, 0); \
    } while (0)

    VBODY(0, 5, 1);  VBODY(1, 5, 1);  VBODY(2, 5, 1);  VBODY(3, 5, 1);
    VBODY(4, 5, 1);  VBODY(5, 5, 1);  VBODY(6, 5, 1);  VBODY(7, 5, 1);
    VBODY(8, 5, 1);  VBODY(9, 5, 1);  VBODY(10, 5, 1); VBODY(11, 5, 1);
    VBODY(12, 5, 1); VBODY(13, 5, 1); VBODY(14, 5, 1); VBODY(15, 5, 1);
    VBODY(16, 5, 1); VBODY(17, 5, 1); VBODY(18, 5, 1); VBODY(19, 5, 1);
    VBODY(20, 5, 1); VBODY(21, 5, 1); VBODY(22, 5, 1); VBODY(23, 5, 1);
    VBODY(24, 5, 1); VBODY(25, 5, 1); VBODY(26, 5, 1); VBODY(27, 5, 1);
    VBODY(28, 5, 1); VBODY(29, 5, 1); VBODY(30, 5, 0); VBODY(31, 0, 0);
#undef VBODY
#undef STAGE

    int gc0 = colBase + colL0;
    int gc1 = colBase + colL1;
    bool v0 = gc0 < V_, v1 = gc1 < V_;
    float b0 = v0 ? bv[gc0] : 0.f;
    float b1 = v1 ? bv[gc1] : 0.f;
    f32x4 accA[4] = {acc00, acc01, acc02, acc03};
    f32x4 accB[4] = {acc10, acc11, acc12, acc13};
#pragma unroll
    for (int mf = 0; mf < 4; ++mf) {
#pragma unroll
        for (int r = 0; r < 4; ++r) {
            int row = mf * 16 + lg * 4 + r;       // batch index
            float l0 = fminf(fmaxf(accA[mf][r] + b0, -50.f), 50.f);
            float l1 = fminf(fmaxf(accB[mf][r] + b1, -50.f), 50.f);
            float e0 = v0 ? __expf(l0 - 50.f) : 0.f;
            float e1 = v1 ? __expf(l1 - 50.f) : 0.f;
            if (v0) e[(size_t)row * VP2 + gc0] = (__bf16)e0;
            if (v1) e[(size_t)row * VP2 + gc1] = (__bf16)e1;
            float s = e0 + e1;
            s += __shfl_xor(s, 1); s += __shfl_xor(s, 2);
            s += __shfl_xor(s, 4); s += __shfl_xor(s, 8);
            if (lr == 0) wsum[wave][row] = s;
        }
    }
    __syncthreads();
    if (threadIdx.x < 64) {
        int row = threadIdx.x;
        float t = wsum[0][row] + wsum[1][row] + wsum[2][row] + wsum[3][row];
        psum[(size_t)row * PSTR + blk] = t;
    }
}

// ------- fused Z-reduce + normalize + outputs (vectorized x4) ---------------
__global__ __launch_bounds__(256) void k_finalz(const __bf16* __restrict__ e,
                                                const float* __restrict__ psum,
                                                const float* __restrict__ pg,
                                                float* __restrict__ out0,
                                                float* __restrict__ out2) {
    int b   = blockIdx.x >> 3;
    int sub = blockIdx.x & 7;
    int tid = threadIdx.x;

    float s = 0.f;
    for (int i = tid; i < NBLK2; i += 256) s += psum[(size_t)b * PSTR + i];
#pragma unroll
    for (int m = 32; m >= 1; m >>= 1) s += __shfl_xor(s, m);
    __shared__ float r[4];
    __shared__ float zsh;
    int wave = tid >> 6, lane = tid & 63;
    if (lane == 0) r[wave] = s;
    __syncthreads();
    if (tid == 0) zsh = 1.f / (r[0] + r[1] + r[2] + r[3]);
    __syncthreads();
    float zinv = zsh;
    float p = pg[b];

    int v4beg = sub * 1563;
    int v4end = v4beg + 1563;
    if (v4end > 12500) v4end = 12500;
    const u16x4* erow = (const u16x4*)(e + (size_t)b * VP2);
    f32x4* o0 = (f32x4*)(out0 + (size_t)b * EXTV);
    f32x4* o2 = (f32x4*)(out2 + (size_t)b * V_);
    for (int v4 = v4beg + tid; v4 < v4end; v4 += 256) {
        u16x4 u = erow[v4];
        f32x4 vd;
        vd[0] = __uint_as_float((unsigned)u[0] << 16) * zinv;
        vd[1] = __uint_as_float((unsigned)u[1] << 16) * zinv;
        vd[2] = __uint_as_float((unsigned)u[2] << 16) * zinv;
        vd[3] = __uint_as_float((unsigned)u[3] << 16) * zinv;
        o2[v4] = vd;
        f32x4 g;
        g[0] = p * vd[0]; g[1] = p * vd[1]; g[2] = p * vd[2]; g[3] = p * vd[3];
        o0[v4] = g;
    }
    if (sub == 7 && tid < 100) out0[(size_t)b * EXTV + V_ + tid] = 0.f;
}

// ---------------- copy-distribution scatter --------------------------------
__global__ __launch_bounds__(256) void k_scatter(const float* __restrict__ attn,
                                                 const int* __restrict__ sid,
                                                 const int* __restrict__ oov,
                                                 const float* __restrict__ pg,
                                                 float* __restrict__ out0) {
    int idx = blockIdx.x * 256 + threadIdx.x;
    if (idx >= B_ * S_) return;
    int b = idx / S_;
    int m = oov[idx];
    int tgt = (m >= 0) ? (V_ + m) : sid[idx];
    float w = (1.f - pg[b]) * attn[idx];
    atomicAdd(out0 + (size_t)b * EXTV + tgt, w);
}

extern "C" void kernel_launch(void* const* d_in, const int* in_sizes, int n_in,
                              void* d_out, int out_size, void* d_ws, size_t ws_size,
                              hipStream_t stream) {
    const float* dec  = (const float*)d_in[0];
    const float* ctx  = (const float*)d_in[1];
    const float* emb  = (const float*)d_in[2];
    const float* attn = (const float*)d_in[3];
    const int*   sid  = (const int*)d_in[4];
    const int*   oov  = (const int*)d_in[5];
    // d_in[6] = vocab_size (known statically = 50000)
    const float* Wm   = (const float*)d_in[7];
    const float* bm   = (const float*)d_in[8];
    const float* Wp   = (const float*)d_in[9];
    const float* bp   = (const float*)d_in[10];
    const float* Wv   = (const float*)d_in[11];
    const float* bv   = (const float*)d_in[12];

    float* out0 = (float*)d_out;                  // final_dist [64][50100]
    float* out1 = out0 + (size_t)B_ * EXTV;       // p_gen      [64]
    float* out2 = out1 + B_;                      // vocab_dist [64][50000]

    __bf16* e    = (__bf16*)d_ws;                            // [64][VP2] bf16
    float*  psum = (float*)((char*)d_ws + (size_t)B_ * VP2 * 2); // [64][PSTR]
    float*  pg   = psum + (size_t)B_ * PSTR;      // [64]
    float*  pmid = pg + 64;                       // [KCH][64][1024]
    __bf16* midb = (__bf16*)(pmid + (size_t)KCH * B_ * H_); // [64][1024]

    k_pgen<<<B_, 256, 0, stream>>>(dec, ctx, emb, Wp, bp, pg, out1);
    dim3 gmid(16, KCH);
    k_gemm_mid<<<gmid, 256, 0, stream>>>(dec, ctx, Wm, pmid);
    k_mid_reduce<<<(B_ * H_) / 256, 256, 0, stream>>>(pmid, bm, midb);
    k_gemm_vocab<<<NBLK2, 256, 0, stream>>>((const __bf16*)midb, Wv, bv, e, psum);
    k_finalz<<<B_ * 8, 256, 0, stream>>>((const __bf16*)e, psum, pg, out0, out2);
    k_scatter<<<(B_ * S_ + 255) / 256, 256, 0, stream>>>(attn, sid, oov, pg, out0);
}